// Round 1
// baseline (81.310 us; speedup 1.0000x reference)
//
#include <hip/hip_runtime.h>
#include <math.h>

#define WIN  48
#define BLK  256
#define HALO (WIN - 1)      // 47
#define ROWS (BLK + HALO)   // 303

// Kernel 1: per-window alpha coefficients.
// alpha[k,c] = (W[0,c] + r_k * W[1,c]) / m[k,c],  r_k = sqrt(q0/q1),
// q_o = sum_w (sum_c x[k+w,c]*W[o,c]/m[k,c])^2   (mean of u is exactly 0 since W rows sum to 0)
__global__ __launch_bounds__(BLK) void pos_win_kernel(
    const float* __restrict__ x,   // [N,3]
    const float* __restrict__ Wm,  // [2,3]
    float* __restrict__ a0, float* __restrict__ a1, float* __restrict__ a2,
    int N, int K)
{
    __shared__ float4 ldsbuf[ROWS];          // rows padded to 4 floats -> b128 reads, conflict-free
    float* lds = (float*)ldsbuf;
    const int t  = threadIdx.x;
    const int k0 = blockIdx.x * BLK;

    // cooperative load of rows k0..k0+302 (clamped; clamped rows only touched by invalid threads)
    for (int i = t; i < ROWS * 3; i += BLK) {
        int row = i / 3;
        int c   = i - row * 3;
        int gr  = k0 + row; if (gr > N - 1) gr = N - 1;
        lds[row * 4 + c] = x[gr * 3 + c];
    }
    __syncthreads();

    const int k = k0 + t;
    if (k >= K) return;

    const float4* l4 = (const float4*)ldsbuf;

    // pass 1: channel means over the window
    float s0 = 0.f, s1 = 0.f, s2 = 0.f;
    #pragma unroll
    for (int w = 0; w < WIN; ++w) {
        float4 v = l4[t + w];
        s0 += v.x; s1 += v.y; s2 += v.z;
    }
    const float inv = 1.0f / (float)WIN;
    const float i0 = 1.0f / (s0 * inv);
    const float i1 = 1.0f / (s1 * inv);
    const float i2 = 1.0f / (s2 * inv);

    const float W00 = Wm[0], W01 = Wm[1], W02 = Wm[2];
    const float W10 = Wm[3], W11 = Wm[4], W12 = Wm[5];

    // pass 2: sum of squares of the projected, mean-free signal
    float q0 = 0.f, q1 = 0.f;
    #pragma unroll
    for (int w = 0; w < WIN; ++w) {
        float4 v = l4[t + w];
        float c0 = v.x * i0, c1 = v.y * i1, c2 = v.z * i2;
        float u0 = W00 * c0 + W01 * c1 + W02 * c2;
        float u1 = W10 * c0 + W11 * c1 + W12 * c2;
        q0 += u0 * u0;
        q1 += u1 * u1;
    }
    const float r = sqrtf(q0 / q1);   // std0/std1 (ddof factor cancels)

    a0[k] = (W00 + r * W10) * i0;
    a1[k] = (W01 + r * W11) * i1;
    a2[k] = (W02 + r * W12) * i2;
}

// Kernel 2: H[n] = sum_c x[n,c] * (sum over windows covering n of alpha[k,c])
__global__ __launch_bounds__(BLK) void pos_scatter_kernel(
    const float* __restrict__ x,
    const float* __restrict__ a0, const float* __restrict__ a1, const float* __restrict__ a2,
    float* __restrict__ H, int N, int K)
{
    __shared__ float b0[ROWS], b1[ROWS], b2[ROWS];
    const int t  = threadIdx.x;
    const int n0 = blockIdx.x * BLK;

    for (int i = t; i < ROWS; i += BLK) {
        int kk = n0 - HALO + i;
        bool ok = (kk >= 0) && (kk < K);
        b0[i] = ok ? a0[kk] : 0.f;
        b1[i] = ok ? a1[kk] : 0.f;
        b2[i] = ok ? a2[kk] : 0.f;
    }
    __syncthreads();

    const int n = n0 + t;
    if (n >= N) return;

    float A0 = 0.f, A1 = 0.f, A2 = 0.f;
    #pragma unroll
    for (int j = 0; j < WIN; ++j) {
        A0 += b0[t + j];
        A1 += b1[t + j];
        A2 += b2[t + j];
    }
    H[n] = x[n * 3 + 0] * A0 + x[n * 3 + 1] * A1 + x[n * 3 + 2] * A2;
}

extern "C" void kernel_launch(void* const* d_in, const int* in_sizes, int n_in,
                              void* d_out, int out_size, void* d_ws, size_t ws_size,
                              hipStream_t stream) {
    const float* rgbs = (const float*)d_in[0];   // [1, N, 3]
    const float* W    = (const float*)d_in[1];   // [2, 3]
    // d_in[2] = b: provably cancels (std is shift-invariant; mean subtraction removes it)

    const int N = in_sizes[0] / 3;
    const int K = N - WIN;

    float* a0 = (float*)d_ws;        // 3 planar arrays of K floats = 4.8 MB
    float* a1 = a0 + K;
    float* a2 = a1 + K;
    float* H  = (float*)d_out;

    const int blocks1 = (K + BLK - 1) / BLK;
    const int blocks2 = (N + BLK - 1) / BLK;

    pos_win_kernel<<<blocks1, BLK, 0, stream>>>(rgbs, W, a0, a1, a2, N, K);
    pos_scatter_kernel<<<blocks2, BLK, 0, stream>>>(rgbs, a0, a1, a2, H, N, K);
}

// Round 2
// 65.464 us; speedup vs baseline: 1.2421x; 1.2421x over previous
//
#include <hip/hip_runtime.h>
#include <math.h>

#define WIN  48
#define HALO 47
#define BLK  256
#define TH   5                 // H outputs per thread (odd -> 20B lane stride, conflict-free)
#define TA   7                 // alphas per thread   (odd -> 28B lane stride, conflict-free)
#define RR   (BLK * TH)        // 1280 H outputs per block
#define RA   (RR + HALO)       // 1327 alphas per block
#define XR   (RR + 2 * HALO)   // 1374 x rows per block

// Fully fused POS extractor.
// alpha[k,c] = (W0c + r_k W1c)/m_kc, r_k = sqrt(q0/q1),
// q_o = sum_{a,b} W_oa W_ob y_a y_b S_ab with y_c = 48/s_c,
// s_c, S_ab = sliding window sums of x_c and x_a*x_b  (O(1) slide per window).
// H[n] = sum_c x[n,c] * sum_{k in [n-47,n] ∩ [0,K)} alpha[k,c]  (second O(1) slide).
__global__ __launch_bounds__(BLK) void pos_fused_kernel(
    const float* __restrict__ x,   // [N,3]
    const float* __restrict__ Wm,  // [2,3]
    float* __restrict__ H, int N, int K)
{
    __shared__ float xs[3][XR + 3];   // +3 pad: tail-thread padding slides read past XR
    __shared__ float as[3][RA + TA];  // pad: tail-thread padding alphas write past RA

    const int t     = threadIdx.x;
    const int n0    = blockIdx.x * RR;
    const int xbase = n0 - HALO;

    // ---- stage x tile, channel-planar (clamped rows only feed padding alphas) ----
    for (int i = t; i < XR * 3; i += BLK) {
        int row = i / 3;
        int c   = i - row * 3;
        int g   = xbase + row;
        g = g < 0 ? 0 : (g > N - 1 ? N - 1 : g);
        xs[c][row] = x[g * 3 + c];
    }
    __syncthreads();

    const float W00 = Wm[0], W01 = Wm[1], W02 = Wm[2];
    const float W10 = Wm[3], W11 = Wm[4], W12 = Wm[5];
    const float c000 = W00*W00, c011 = W01*W01, c022 = W02*W02;
    const float c001 = 2.f*W00*W01, c002 = 2.f*W00*W02, c012 = 2.f*W01*W02;
    const float c100 = W10*W10, c111 = W11*W11, c122 = W12*W12;
    const float c101 = 2.f*W10*W11, c102 = 2.f*W10*W12, c112 = 2.f*W11*W12;

    // ---- phase A: alphas via sliding cross-moments (threads 0..189 active) ----
    const int abase = t * TA;
    if (abase < RA) {
        float s0=0.f,s1=0.f,s2=0.f;
        float S00=0.f,S01=0.f,S02=0.f,S11=0.f,S12=0.f,S22=0.f;
        float st0[TA-1], st1[TA-1], st2[TA-1];   // statically-indexed stash (full unroll)
        #pragma unroll
        for (int w = 0; w < WIN; ++w) {
            float x0 = xs[0][abase+w], x1 = xs[1][abase+w], x2 = xs[2][abase+w];
            if (w < TA-1) { st0[w]=x0; st1[w]=x1; st2[w]=x2; }
            s0+=x0; s1+=x1; s2+=x2;
            S00=fmaf(x0,x0,S00); S01=fmaf(x0,x1,S01); S02=fmaf(x0,x2,S02);
            S11=fmaf(x1,x1,S11); S12=fmaf(x1,x2,S12); S22=fmaf(x2,x2,S22);
        }
        #pragma unroll
        for (int j = 0; j < TA; ++j) {
            if (j > 0) {
                float xn0=xs[0][abase+HALO+j], xn1=xs[1][abase+HALO+j], xn2=xs[2][abase+HALO+j];
                float xo0=st0[j-1], xo1=st1[j-1], xo2=st2[j-1];
                s0 += xn0-xo0; s1 += xn1-xo1; s2 += xn2-xo2;
                S00 += fmaf(xn0,xn0,-xo0*xo0); S01 += fmaf(xn0,xn1,-xo0*xo1);
                S02 += fmaf(xn0,xn2,-xo0*xo2); S11 += fmaf(xn1,xn1,-xo1*xo1);
                S12 += fmaf(xn1,xn2,-xo1*xo2); S22 += fmaf(xn2,xn2,-xo2*xo2);
            }
            float y0 = 48.f/s0, y1 = 48.f/s1, y2 = 48.f/s2;
            float p00 = y0*y0*S00, p11 = y1*y1*S11, p22 = y2*y2*S22;
            float p01 = y0*y1*S01, p02 = y0*y2*S02, p12 = y1*y2*S12;
            float q0 = c000*p00 + c011*p11 + c022*p22 + c001*p01 + c002*p02 + c012*p12;
            float q1 = c100*p00 + c111*p11 + c122*p22 + c101*p01 + c102*p02 + c112*p12;
            float r  = sqrtf(q0 / q1);              // NaN for padding windows -> selected away
            int  k   = xbase + abase + j;
            bool ok  = (k >= 0) & (k < K);
            as[0][abase+j] = ok ? (W00 + r*W10)*y0 : 0.f;
            as[1][abase+j] = ok ? (W01 + r*W11)*y1 : 0.f;
            as[2][abase+j] = ok ? (W02 + r*W12)*y2 : 0.f;
        }
    }
    __syncthreads();

    // ---- phase B: H via sliding alpha sums ----
    const int hbase = t * TH;
    float A0=0.f, A1=0.f, A2=0.f;
    float sa0[TH-1], sa1[TH-1], sa2[TH-1];
    #pragma unroll
    for (int w = 0; w < WIN; ++w) {
        float a0 = as[0][hbase+w], a1 = as[1][hbase+w], a2 = as[2][hbase+w];
        if (w < TH-1) { sa0[w]=a0; sa1[w]=a1; sa2[w]=a2; }
        A0+=a0; A1+=a1; A2+=a2;
    }
    #pragma unroll
    for (int j = 0; j < TH; ++j) {
        if (j > 0) {
            A0 += as[0][hbase+HALO+j] - sa0[j-1];
            A1 += as[1][hbase+HALO+j] - sa1[j-1];
            A2 += as[2][hbase+HALO+j] - sa2[j-1];
        }
        int xrow = hbase + j + HALO;     // x row for n = n0 + hbase + j
        float h = xs[0][xrow]*A0 + xs[1][xrow]*A1 + xs[2][xrow]*A2;
        int n = n0 + hbase + j;
        if (n < N) H[n] = h;
    }
}

extern "C" void kernel_launch(void* const* d_in, const int* in_sizes, int n_in,
                              void* d_out, int out_size, void* d_ws, size_t ws_size,
                              hipStream_t stream) {
    const float* rgbs = (const float*)d_in[0];   // [1, N, 3]
    const float* W    = (const float*)d_in[1];   // [2, 3]
    // d_in[2] = b: cancels exactly (std shift-invariant; mean subtraction removes it)

    const int N = in_sizes[0] / 3;
    const int K = N - WIN;
    float* H = (float*)d_out;

    const int blocks = (N + RR - 1) / RR;        // 313
    pos_fused_kernel<<<blocks, BLK, 0, stream>>>(rgbs, W, H, N, K);
}

// Round 5
// 64.873 us; speedup vs baseline: 1.2534x; 1.0091x over previous
//
#include <hip/hip_runtime.h>
#include <math.h>

#define WIN  48
#define HALO 47
#define BLK  256
#define TH   7                  // H outputs/thread (odd -> 28B stride, conflict-free)
#define TA   9                  // alphas/thread    (odd -> 36B stride, conflict-free)
#define RR   (BLK * TH)         // 1792 H outputs per block -> 224 blocks = 1/CU
#define RA   (RR + HALO)        // 1839 alphas per block
#define XR   (RR + 2 * HALO)    // 1886 x rows per block
#define XPAD 16
#define APAD 8

// Fused POS extractor (see round-1/2 derivation):
// alpha[k,c] = (W0c + r_k W1c)/m_kc, r_k = sqrt(q0/q1),
// q_o from 9 sliding cross-moments (O(1) slide); H[n] = x[n,:]·(sliding sum of alpha).
__global__ __launch_bounds__(BLK) void pos_fused_kernel(
    const float* __restrict__ x,   // [N,3]
    const float* __restrict__ Wm,  // [2,3]
    float* __restrict__ H, int N, int K)
{
    __shared__ float xs[3][XR + XPAD];
    __shared__ float as[3][RA + APAD];

    const int t     = threadIdx.x;
    const int n0    = blockIdx.x * RR;
    const int xbase = n0 - HALO;

    // ---- stage x tile, channel-planar ----
    const bool interior = (xbase >= 0) && (xbase + XR <= N);
    if (interior) {
        const int F0  = xbase * 3;
        const int pre = (4 - (F0 & 3)) & 3;          // scalar prologue to 16B alignment
        if (t < pre) {
            int f = F0 + t, r = f / 3, c = f - 3 * r;
            xs[c][r - xbase] = x[f];
        }
        const int n4  = (XR * 3 - pre) >> 2;
        const int rem = (XR * 3 - pre) & 3;
        const float4* x4 = (const float4*)(x + F0 + pre);
        for (int i = t; i < n4; i += BLK) {
            float4 v = x4[i];
            int f = F0 + pre + 4 * i;
            int r = f / 3, c = f - 3 * r; r -= xbase;
            xs[c][r] = v.x; if (++c == 3) { c = 0; ++r; }
            xs[c][r] = v.y; if (++c == 3) { c = 0; ++r; }
            xs[c][r] = v.z; if (++c == 3) { c = 0; ++r; }
            xs[c][r] = v.w;
        }
        if (t < rem) {
            int f = F0 + pre + 4 * n4 + t, r = f / 3, c = f - 3 * r;
            xs[c][r - xbase] = x[f];
        }
    } else {
        for (int i = t; i < XR * 3; i += BLK) {      // edge blocks: clamped scalar
            int r = i / 3, c = i - 3 * r;
            int g = xbase + r;
            g = g < 0 ? 0 : (g > N - 1 ? N - 1 : g);
            xs[c][r] = x[g * 3 + c];
        }
    }
    __syncthreads();

    const float W00 = Wm[0], W01 = Wm[1], W02 = Wm[2];
    const float W10 = Wm[3], W11 = Wm[4], W12 = Wm[5];
    const float c000 = W00*W00, c011 = W01*W01, c022 = W02*W02;
    const float c001 = 2.f*W00*W01, c002 = 2.f*W00*W02, c012 = 2.f*W01*W02;
    const float c100 = W10*W10, c111 = W11*W11, c122 = W12*W12;
    const float c101 = 2.f*W10*W11, c102 = 2.f*W10*W12, c112 = 2.f*W11*W12;

    // ---- phase A: alphas via sliding cross-moments (threads 0..204) ----
    const int abase = t * TA;
    if (abase < RA) {
        float s0=0.f,s1=0.f,s2=0.f;
        float S00=0.f,S01=0.f,S02=0.f,S11=0.f,S12=0.f,S22=0.f;
        float st0[TA-1], st1[TA-1], st2[TA-1];     // statically indexed (full unroll)
        #pragma unroll
        for (int w = 0; w < WIN; ++w) {
            float x0 = xs[0][abase+w], x1 = xs[1][abase+w], x2 = xs[2][abase+w];
            if (w < TA-1) { st0[w]=x0; st1[w]=x1; st2[w]=x2; }
            s0+=x0; s1+=x1; s2+=x2;
            S00=fmaf(x0,x0,S00); S01=fmaf(x0,x1,S01); S02=fmaf(x0,x2,S02);
            S11=fmaf(x1,x1,S11); S12=fmaf(x1,x2,S12); S22=fmaf(x2,x2,S22);
        }
        #pragma unroll
        for (int j = 0; j < TA; ++j) {
            if (j > 0) {
                float xn0=xs[0][abase+HALO+j], xn1=xs[1][abase+HALO+j], xn2=xs[2][abase+HALO+j];
                float xo0=st0[j-1], xo1=st1[j-1], xo2=st2[j-1];
                s0 += xn0-xo0; s1 += xn1-xo1; s2 += xn2-xo2;
                S00 += fmaf(xn0,xn0,-xo0*xo0); S01 += fmaf(xn0,xn1,-xo0*xo1);
                S02 += fmaf(xn0,xn2,-xo0*xo2); S11 += fmaf(xn1,xn1,-xo1*xo1);
                S12 += fmaf(xn1,xn2,-xo1*xo2); S22 += fmaf(xn2,xn2,-xo2*xo2);
            }
            float y0 = 48.f/s0, y1 = 48.f/s1, y2 = 48.f/s2;
            float p00 = y0*y0*S00, p11 = y1*y1*S11, p22 = y2*y2*S22;
            float p01 = y0*y1*S01, p02 = y0*y2*S02, p12 = y1*y2*S12;
            float q0 = c000*p00 + c011*p11 + c022*p22 + c001*p01 + c002*p02 + c012*p12;
            float q1 = c100*p00 + c111*p11 + c122*p22 + c101*p01 + c102*p02 + c112*p12;
            float r  = sqrtf(q0 / q1);             // garbage only for unused padding alphas
            int  k   = xbase + abase + j;
            bool ok  = (k >= 0) & (k < K);
            as[0][abase+j] = ok ? (W00 + r*W10)*y0 : 0.f;
            as[1][abase+j] = ok ? (W01 + r*W11)*y1 : 0.f;
            as[2][abase+j] = ok ? (W02 + r*W12)*y2 : 0.f;
        }
    }
    __syncthreads();

    // ---- phase B: H via sliding alpha sums ----
    const int hbase = t * TH;
    float A0=0.f, A1=0.f, A2=0.f;
    float sa0[TH-1], sa1[TH-1], sa2[TH-1];
    #pragma unroll
    for (int w = 0; w < WIN; ++w) {
        float a0 = as[0][hbase+w], a1 = as[1][hbase+w], a2 = as[2][hbase+w];
        if (w < TH-1) { sa0[w]=a0; sa1[w]=a1; sa2[w]=a2; }
        A0+=a0; A1+=a1; A2+=a2;
    }
    #pragma unroll
    for (int j = 0; j < TH; ++j) {
        if (j > 0) {
            A0 += as[0][hbase+HALO+j] - sa0[j-1];
            A1 += as[1][hbase+HALO+j] - sa1[j-1];
            A2 += as[2][hbase+HALO+j] - sa2[j-1];
        }
        int xrow = hbase + j + HALO;               // x row for n = n0 + hbase + j
        float h = xs[0][xrow]*A0 + xs[1][xrow]*A1 + xs[2][xrow]*A2;
        int n = n0 + hbase + j;
        if (n < N) H[n] = h;
    }
}

extern "C" void kernel_launch(void* const* d_in, const int* in_sizes, int n_in,
                              void* d_out, int out_size, void* d_ws, size_t ws_size,
                              hipStream_t stream) {
    const float* rgbs = (const float*)d_in[0];   // [1, N, 3]
    const float* W    = (const float*)d_in[1];   // [2, 3]
    // d_in[2] = b: cancels exactly (std shift-invariant; mean subtraction removes it)

    const int N = in_sizes[0] / 3;
    const int K = N - WIN;
    float* H = (float*)d_out;

    const int blocks = (N + RR - 1) / RR;        // 224 -> one block per CU
    pos_fused_kernel<<<blocks, BLK, 0, stream>>>(rgbs, W, H, N, K);
}